// Round 14
// baseline (1843.602 us; speedup 1.0000x reference)
//
#include <hip/hip_runtime.h>
#include <cstdint>
#include <cmath>

typedef short bf16x8 __attribute__((ext_vector_type(8)));
typedef float f32x4 __attribute__((ext_vector_type(4)));

#define AS_GLOBAL(p) (const __attribute__((address_space(1))) void*)(p)
#define AS_LDS(p)    (__attribute__((address_space(3))) void*)(p)

// SCALE * log2(e) folded into Q epilogue: 2^-5 * 1.44269504
#define QSCALE 0.04508422002778f

__device__ inline float b2f(unsigned short u) {
    union { unsigned int i; float f; } c; c.i = ((unsigned int)u) << 16; return c.f;
}
__device__ inline unsigned short f2b(float f) {
    return (unsigned short)((__float_as_uint(f) + 0x8000u) >> 16);
}
// HW packed f32->bf16 (RTNE), 1 inst per 2 floats (T12 recipe; no builtin on gfx950)
__device__ inline unsigned cvt_pk_bf16u(float lo, float hi) {
    unsigned r;
    asm("v_cvt_pk_bf16_f32 %0, %1, %2" : "=v"(r) : "v"(lo), "v"(hi));
    return r;
}
// fast GELU: x * sigmoid(1.5957691x + 0.071354816x^3), evaluated in exp2 domain.
__device__ inline float fast_gelu(float x) {
    float arg = -x * (2.30223674f + 0.10294946f * x * x);
    float t = exp2f(arg);
    return x * __builtin_amdgcn_rcpf(1.f + t);
}

// swizzled LDS fragment read: row r (pitch 128 B), logical 16B-chunk lc, chunk ^= r&7
__device__ inline bf16x8 ldsfrag(const unsigned short* SM, int base_sh, int r, int lc) {
    return *(const bf16x8*)((const char*)SM + base_sh * 2 + r * 128 + ((lc ^ (r & 7)) << 4));
}

// ---------------- weight transpose+cast: W[K][N] (f32) -> Wt[N][K] (bf16) ----------------
__global__ __launch_bounds__(256) void transpose_f32_to_bf16(
    const float* __restrict__ W, unsigned short* __restrict__ Wt, int K, int N)
{
    __shared__ unsigned short sh[32][33];
    int n0 = blockIdx.x * 32;
    int k0 = blockIdx.y * 32;
    int tr = threadIdx.x >> 5;
    int tc = threadIdx.x & 31;
#pragma unroll
    for (int i = 0; i < 4; i++)
        sh[tr + i * 8][tc] = f2b(W[(size_t)(k0 + tr + i * 8) * N + n0 + tc]);
    __syncthreads();
#pragma unroll
    for (int i = 0; i < 4; i++)
        Wt[(size_t)(n0 + tr + i * 8) * K + k0 + tc] = sh[tc][tr + i * 8];
}

// fused 3x 1024x1024 transpose (z selects Wq->WqkT, Wk->WqkT+1M, Wv->WvT)
__global__ __launch_bounds__(256) void transpose3_f32_to_bf16(
    const float* __restrict__ Wq, const float* __restrict__ Wk,
    const float* __restrict__ Wv, unsigned short* __restrict__ WqkT,
    unsigned short* __restrict__ WvT)
{
    __shared__ unsigned short sh[32][33];
    const float* W = (blockIdx.z == 0) ? Wq : (blockIdx.z == 1) ? Wk : Wv;
    unsigned short* Wt = (blockIdx.z == 0) ? WqkT
                        : (blockIdx.z == 1) ? (WqkT + 1048576) : WvT;
    int n0 = blockIdx.x * 32;
    int k0 = blockIdx.y * 32;
    int tr = threadIdx.x >> 5;
    int tc = threadIdx.x & 31;
#pragma unroll
    for (int i = 0; i < 4; i++)
        sh[tr + i * 8][tc] = f2b(W[(size_t)(k0 + tr + i * 8) * 1024 + n0 + tc]);
    __syncthreads();
#pragma unroll
    for (int i = 0; i < 4; i++)
        Wt[(size_t)(n0 + tr + i * 8) * 1024 + k0 + tc] = sh[tc][tr + i * 8];
}

// ---------------- bias concat: bqk = [bq | bk] ----------------
__global__ __launch_bounds__(256) void concat_bias(const float* __restrict__ bq,
                                                   const float* __restrict__ bk,
                                                   float* __restrict__ bqk)
{
    int i = blockIdx.x * 256 + threadIdx.x;
    bqk[i] = (i < 1024) ? bq[i] : bk[i - 1024];
}

// ---------------- layernorm: fp32 in -> bf16 out; 2 rows/block, 8 elems/thread ----------------
__global__ __launch_bounds__(256) void layernorm_k(
    const float* __restrict__ x, const float* __restrict__ gamma,
    const float* __restrict__ beta, unsigned short* __restrict__ out)
{
    const int t   = threadIdx.x;
    const int row = blockIdx.x * 2 + (t >> 7);
    const int c   = (t & 127) * 8;
    const float* xp = x + (size_t)row * 1024 + c;
    f32x4 v0 = *(const f32x4*)(xp);
    f32x4 v1 = *(const f32x4*)(xp + 4);
    float s  = v0[0] + v0[1] + v0[2] + v0[3] + v1[0] + v1[1] + v1[2] + v1[3];
    float s2 = v0[0]*v0[0] + v0[1]*v0[1] + v0[2]*v0[2] + v0[3]*v0[3]
             + v1[0]*v1[0] + v1[1]*v1[1] + v1[2]*v1[2] + v1[3]*v1[3];
#pragma unroll
    for (int off = 32; off >= 1; off >>= 1) {
        s  += __shfl_xor(s,  off);
        s2 += __shfl_xor(s2, off);
    }
    __shared__ float red[8];
    const int w = t >> 6;                 // wave 0..3; waves {0,1}=row0, {2,3}=row1
    if ((t & 63) == 0) { red[w] = s; red[4 + w] = s2; }
    __syncthreads();
    const int base = w & 2;
    s  = red[base] + red[base + 1];
    s2 = red[4 + base] + red[5 + base];
    float mu  = s * (1.f / 1024.f);
    float var = s2 * (1.f / 1024.f) - mu * mu;
    float rs  = rsqrtf(var + 1e-5f);
    f32x4 g0 = *(const f32x4*)(gamma + c);
    f32x4 g1 = *(const f32x4*)(gamma + c + 4);
    f32x4 b0 = *(const f32x4*)(beta + c);
    f32x4 b1 = *(const f32x4*)(beta + c + 4);
    uint4 pk;
    {
        float o0 = (v0[0] - mu) * rs * g0[0] + b0[0];
        float o1 = (v0[1] - mu) * rs * g0[1] + b0[1];
        float o2 = (v0[2] - mu) * rs * g0[2] + b0[2];
        float o3 = (v0[3] - mu) * rs * g0[3] + b0[3];
        float o4 = (v1[0] - mu) * rs * g1[0] + b1[0];
        float o5 = (v1[1] - mu) * rs * g1[1] + b1[1];
        float o6 = (v1[2] - mu) * rs * g1[2] + b1[2];
        float o7 = (v1[3] - mu) * rs * g1[3] + b1[3];
        pk.x = (unsigned)f2b(o0) | ((unsigned)f2b(o1) << 16);
        pk.y = (unsigned)f2b(o2) | ((unsigned)f2b(o3) << 16);
        pk.z = (unsigned)f2b(o4) | ((unsigned)f2b(o5) << 16);
        pk.w = (unsigned)f2b(o6) | ((unsigned)f2b(o7) << 16);
    }
    *(uint4*)(out + (size_t)row * 1024 + c) = pk;
}

// ---------------- 256-wide 8-phase MFMA GEMM (round-11 schedule) ----------------
// BM=256, BK=64, 512 threads = 8 waves. Wave grid: WGN = BN/64 waves along N,
// 8/WGN along M -> per-wave sub-tile (32*WGN rows) x 64 cols.
// Phase pipeline: phase p issues phase p+1's ds_reads BEFORE the phase barrier,
// waits counted lgkmcnt + sched_barrier, then runs the MFMA cluster.
// STAGE split 2 gload_lds per phase; tile-end vmcnt(0)+barrier (proven; counted
// vmcnt was null-to-negative here twice — the drain is already covered).
// Decode: SMALLM=0: m-fastest within XCD (FETCH -33% proven, round 12);
//   SMALLM=1 (M=1024): m_idx=j>>3, n_idx=xcd*8+(j&7).
// MODE 1: bf16 out = fast_gelu(v + bias[col])
// MODE 2: f32 out = resid[idx] + v + bias[col]   (resid may alias out)
// MODE 3: bf16 out = v + bias[row]               (V^T GEMM)
// MODE 5: bf16 out = (v + bias[col]) * (col<1024 ? QSCALE : 1)
template<int MODE, int NBNL, int BN, int SMALLM = 0>
__global__ __launch_bounds__(512, 2) void gemm256(
    const unsigned short* __restrict__ A,
    const unsigned short* __restrict__ Bt,
    const float* __restrict__ bias,
    const float* __restrict__ resid,
    void* __restrict__ outp,
    int M, int N, int K)
{
    constexpr int NFR = BN / 64;          // B row-groups to stage per thread
    constexpr int WGN = BN / 64;          // waves along N (4 or 2)
    constexpr int WM  = 2 * WGN;          // m-frags per wave (8 or 4)
    constexpr int HM  = WM / 2;           // m-frags per phase (4 or 2)
    extern __shared__ unsigned short LDS[];   // [A buf0|A buf1|B buf0|B buf1]

    const int t   = threadIdx.x;
    const int bi  = blockIdx.x;
    const int xcd = bi & 7;
    const int j   = bi >> 3;
    int m_idx, n_idx;
    if (SMALLM) {                         // M = 1024: 4 m-tiles x (8*8) n-tiles
        m_idx = j >> 3;
        n_idx = xcd * 8 + (j & 7);
    } else {                              // m-fastest within XCD (less L2 thrash)
        const int mper = M >> 11;         // m-tiles per XCD (power of 2)
        m_idx = xcd * mper + (j & (mper - 1));
        n_idx = j >> __builtin_ctz(mper);
    }
    const int m0 = m_idx * 256;
    const int n0 = n_idx * BN;

    const int w    = t >> 6;
    const int lane = t & 63;
    const int l15  = lane & 15;
    const int q    = lane >> 4;
    const int wmb  = (w / WGN) * (WM * 16);   // row base of wave's sub-tile
    const int wnb  = (w % WGN) * 64;          // col base of wave's sub-tile
    const int xsw  = (l15 & 7) << 4;          // read-side swizzle (byte)

    const int trow = t >> 3;
    const int csrc = ((t & 7) ^ (trow & 7)) << 3;     // element offset in row
    const unsigned short* As0 = A  + (size_t)(m0 + trow) * K + csrc;
    const unsigned short* Bs0 = Bt + (size_t)(n0 + trow) * K + csrc;

    f32x4 acc[WM][4];
#pragma unroll
    for (int i = 0; i < WM; i++)
#pragma unroll
        for (int n = 0; n < 4; n++) acc[i][n] = (f32x4)0.f;

    // staging split into 4 parts, 2 gload_lds each (BN=128: part 3 empty)
    auto STAGEP = [&](int Tn, int part) {
        const int bsel = Tn & 1;
        const size_t kk = (size_t)Tn << 6;
        if (part < 2) {
#pragma unroll
            for (int la = part * 2; la < part * 2 + 2; la++)
                __builtin_amdgcn_global_load_lds(
                    AS_GLOBAL(As0 + (size_t)la * 64 * K + kk),
                    AS_LDS(LDS + bsel * 16384 + la * 4096 + w * 512), 16, 0, 0);
        } else {
#pragma unroll
            for (int lb = (part - 2) * 2; lb < (part - 2) * 2 + 2; lb++)
                if (lb < NFR)
                    __builtin_amdgcn_global_load_lds(
                        AS_GLOBAL(Bs0 + (size_t)lb * 64 * K + kk),
                        AS_LDS(LDS + 32768 + bsel * (BN * 64) + lb * 4096 + w * 512), 16, 0, 0);
        }
    };
    auto RDAF = [&](const char* Ab, int ks, int mh, bf16x8* dst) {
        const int colx = ((ks * 64 + q * 16) ^ xsw);
#pragma unroll
        for (int m4 = 0; m4 < HM; m4++)
            dst[m4] = *(const bf16x8*)(Ab + (wmb + (mh * HM + m4) * 16 + l15) * 128 + colx);
    };
    auto RDBV = [&](const char* Bb, int ks, bf16x8* dst) {
        const int colx = ((ks * 64 + q * 16) ^ xsw);
#pragma unroll
        for (int ni = 0; ni < 4; ni++)
            dst[ni] = *(const bf16x8*)(Bb + (wnb + ni * 16 + l15) * 128 + colx);
    };
    auto MM = [&](int mh, bf16x8* afs, bf16x8* bvs) {
        __builtin_amdgcn_s_setprio(1);
#pragma unroll
        for (int m4 = 0; m4 < HM; m4++)
#pragma unroll
            for (int ni = 0; ni < 4; ni++)
                acc[mh * HM + m4][ni] = __builtin_amdgcn_mfma_f32_16x16x32_bf16(
                    afs[m4], bvs[ni], acc[mh * HM + m4][ni], 0, 0, 0);
        __builtin_amdgcn_s_setprio(0);
        __builtin_amdgcn_sched_barrier(0);
    };

    bf16x8 afA[HM], afB[HM], bvA[4], bvB[4];

    // prologue: stage tile 0 fully, drain, read phase-0 fragments
    STAGEP(0, 0); STAGEP(0, 1); STAGEP(0, 2); STAGEP(0, 3);
    asm volatile("s_waitcnt vmcnt(0)" ::: "memory");
    __builtin_amdgcn_s_barrier();
    RDBV((const char*)LDS + 65536, 0, bvA);
    RDAF((const char*)LDS, 0, 0, afA);

    const int NT = K >> 6;
    for (int T = 0; T < NT; T++) {
        const char* Ab = (const char*)LDS + (T & 1) * 32768;
        const char* Bb = (const char*)LDS + 65536 + (T & 1) * (BN * 128);
        const bool pf = (T + 1 < NT);

        // phase 0: consume (ks0,mh0)=afA,bvA ; prefetch afB=(ks0,mh1)
        RDAF(Ab, 0, 1, afB);
        if (pf) STAGEP(T + 1, 0);
        __builtin_amdgcn_s_barrier();
        if (BN == 256) asm volatile("s_waitcnt lgkmcnt(4)" ::: "memory");
        else           asm volatile("s_waitcnt lgkmcnt(2)" ::: "memory");
        __builtin_amdgcn_sched_barrier(0);
        MM(0, afA, bvA);

        // phase 1: consume (ks0,mh1)=afB,bvA ; prefetch bvB(ks1), afA=(ks1,mh0)
        RDBV(Bb, 1, bvB);
        RDAF(Ab, 1, 0, afA);
        if (pf) STAGEP(T + 1, 1);
        __builtin_amdgcn_s_barrier();
        if (BN == 256) asm volatile("s_waitcnt lgkmcnt(8)" ::: "memory");
        else           asm volatile("s_waitcnt lgkmcnt(6)" ::: "memory");
        __builtin_amdgcn_sched_barrier(0);
        MM(1, afB, bvA);

        // phase 2: consume (ks1,mh0)=afA,bvB ; prefetch afB=(ks1,mh1)
        RDAF(Ab, 1, 1, afB);
        if (pf) STAGEP(T + 1, 2);
        __builtin_amdgcn_s_barrier();
        if (BN == 256) asm volatile("s_waitcnt lgkmcnt(4)" ::: "memory");
        else           asm volatile("s_waitcnt lgkmcnt(2)" ::: "memory");
        __builtin_amdgcn_sched_barrier(0);
        MM(0, afA, bvB);

        // phase 3: consume (ks1,mh1)=afB,bvB ; lgkmcnt(0) -> WAR-safe for T+1 staging
        if (pf) STAGEP(T + 1, 3);
        __builtin_amdgcn_s_barrier();
        asm volatile("s_waitcnt lgkmcnt(0)" ::: "memory");
        __builtin_amdgcn_sched_barrier(0);
        MM(1, afB, bvB);

        // tile boundary: drain staged loads, then prefetch next tile's phase-0 frags
        asm volatile("s_waitcnt vmcnt(0)" ::: "memory");
        __builtin_amdgcn_s_barrier();
        if (pf) {
            const char* AbN = (const char*)LDS + ((T + 1) & 1) * 32768;
            const char* BbN = (const char*)LDS + 65536 + ((T + 1) & 1) * (BN * 128);
            RDBV(BbN, 0, bvA);
            RDAF(AbN, 0, 0, afA);
        }
    }

    const float qsc = (MODE == 5 && n0 < 1024) ? QSCALE : 1.f;
#pragma unroll
    for (int mi = 0; mi < WM; mi++) {
        const int gr0 = m0 + wmb + mi * 16 + q * 4;
#pragma unroll
        for (int ni = 0; ni < 4; ni++) {
            const int gc = n0 + wnb + ni * 16 + l15;
            const float bv = (MODE == 3) ? 0.f : bias[gc];
#pragma unroll
            for (int r = 0; r < 4; r++) {
                const int gr = gr0 + r;
                float v = acc[mi][ni][r] + ((MODE == 3) ? bias[gr] : bv);
                if (MODE == 1) {
                    ((unsigned short*)outp)[(size_t)gr * N + gc] = f2b(fast_gelu(v));
                } else if (MODE == 2) {
                    ((float*)outp)[(size_t)gr * N + gc] = resid[(size_t)gr * N + gc] + v;
                } else if (MODE == 3) {
                    ((unsigned short*)outp)[(size_t)gr * N + gc] = f2b(v);
                } else { // MODE 5
                    ((unsigned short*)outp)[(size_t)gr * N + gc] = f2b(v * qsc);
                }
            }
        }
    }
}

// ---------------- MFMA flash attention v6 ----------------
// grid = 1024. XCD-locality decode: qt = blk>>7, bh = blk&127.
// 4 waves x 32 q-rows; 16 K-tiles of 64. l row-sum via MFMA ones-trick,
// P/O bf16 packing via v_cvt_pk_bf16_f32. Residual read xres, output xout.
__global__ __launch_bounds__(256, 4) void attn_k(
    const unsigned short* __restrict__ qkb,
    const unsigned short* __restrict__ vtb,
    const float* __restrict__ xres,
    float* __restrict__ xout)
{
    __shared__ unsigned short SM[20480];

    const int t    = threadIdx.x;
    const int blk  = blockIdx.x;
    const int qt   = blk >> 7;
    const int bh   = blk & 127;
    const int h    = bh & 15;
    const int b    = bh >> 4;
    const int w    = t >> 6;
    const int lane = t & 63;
    const int l15  = lane & 15;
    const int quad = lane >> 4;
    const int wrow = w * 32;

    const int sr  = t >> 3;                       // 0..31
    const int slc = (t & 7) ^ (sr & 7);
    const unsigned short* Qsrc = qkb + ((size_t)(b * 1024 + qt * 128 + sr)) * 2048 + h * 64 + slc * 8;
    const unsigned short* Ksrc = qkb + ((size_t)(b * 1024 + sr)) * 2048 + 1024 + h * 64 + slc * 8;
    const unsigned short* Vsrc = vtb + ((size_t)(h * 64 + sr)) * 8192 + (size_t)b * 1024 + slc * 8;

    auto GLL = [&](const unsigned short* g, int sh) {
        __builtin_amdgcn_global_load_lds(AS_GLOBAL(g), AS_LDS(SM + sh + w * 512), 16, 0, 0);
    };

    // ---- prologue: stage Q (128 rows), K[0], K[1], V[0] ----
#pragma unroll
    for (int c = 0; c < 4; c++) GLL(Qsrc + (size_t)c * 32 * 2048, c * 2048);
#pragma unroll
    for (int c = 0; c < 2; c++) GLL(Ksrc + (size_t)c * 32 * 2048, 8192 + c * 2048);
#pragma unroll
    for (int c = 0; c < 2; c++) GLL(Ksrc + (size_t)(64 + c * 32) * 2048, 12288 + c * 2048);
#pragma unroll
    for (int c = 0; c < 2; c++) GLL(Vsrc + (size_t)c * 32 * 8192, 16384 + c * 2048);
    asm volatile("s_waitcnt vmcnt(0)" ::: "memory");
    __builtin_amdgcn_s_barrier();

    bf16x8 qf[2][2];
#pragma unroll
    for (int nt2 = 0; nt2 < 2; nt2++)
#pragma unroll
        for (int kd = 0; kd < 2; kd++)
            qf[nt2][kd] = ldsfrag(SM, 0, wrow + nt2 * 16 + l15, kd * 4 + quad);

    const bf16x8 onesv = (bf16x8)(short)0x3F80;   // bf16 1.0 x8
    float m_s[2] = { -1e30f, -1e30f };
    f32x4 l_acc[2] = { (f32x4)0.f, (f32x4)0.f };
    f32x4 O[2][4];
#pragma unroll
    for (int nt2 = 0; nt2 < 2; nt2++)
#pragma unroll
        for (int dt = 0; dt < 4; dt++) O[nt2][dt] = (f32x4)0.f;

    for (int kt = 0; kt < 16; ++kt) {
        const int cur = kt & 1;
        if (kt > 0) {
            const unsigned short* vs = Vsrc + kt * 64;
            GLL(vs, 16384);
            GLL(vs + (size_t)32 * 8192, 16384 + 2048);
        }

        // ---- S^T = K Q^T ----
        f32x4 s[4][2];
#pragma unroll
        for (int mt = 0; mt < 4; mt++) {
            bf16x8 kf0 = ldsfrag(SM, 8192 + cur * 4096, mt * 16 + l15, quad);
            bf16x8 kf1 = ldsfrag(SM, 8192 + cur * 4096, mt * 16 + l15, 4 + quad);
#pragma unroll
            for (int nt2 = 0; nt2 < 2; nt2++) {
                f32x4 a = (f32x4)0.f;
                a = __builtin_amdgcn_mfma_f32_16x16x32_bf16(kf0, qf[nt2][0], a, 0, 0, 0);
                a = __builtin_amdgcn_mfma_f32_16x16x32_bf16(kf1, qf[nt2][1], a, 0, 0, 0);
                s[mt][nt2] = a;
            }
        }

        // ---- online softmax (exp2 domain), defer-max THR=0 (exact);
        //      exp -> cvt_pk -> P^T LDS store fused; l via MFMA below ----
#pragma unroll
        for (int nt2 = 0; nt2 < 2; nt2++) {
            float tm = -1e30f;
#pragma unroll
            for (int mt = 0; mt < 4; mt++) {
                f32x4 sv = s[mt][nt2];
                tm = fmaxf(tm, fmaxf(fmaxf(sv[0], sv[1]), fmaxf(sv[2], sv[3])));
            }
            tm = fmaxf(tm, __shfl_xor(tm, 16));
            tm = fmaxf(tm, __shfl_xor(tm, 32));
            if (!__all(tm <= m_s[nt2])) {
                float nm    = fmaxf(m_s[nt2], tm);
                float alpha = exp2f(m_s[nt2] - nm);
                m_s[nt2] = nm;
                l_acc[nt2] *= alpha;
#pragma unroll
                for (int dt = 0; dt < 4; dt++) O[nt2][dt] *= alpha;
            }
            const float nm = m_s[nt2];
            const int r = wrow + nt2 * 16 + l15;
#pragma unroll
            for (int mt = 0; mt < 4; mt++) {
                float p0 = exp2f(s[mt][nt2][0] - nm);
                float p1 = exp2f(s[mt][nt2][1] - nm);
                float p2 = exp2f(s[mt][nt2][2] - nm);
                float p3 = exp2f(s[mt][nt2][3] - nm);
                uint2 pk;
                pk.x = cvt_pk_bf16u(p0, p1);
                pk.y = cvt_pk_bf16u(p2, p3);
                *(uint2*)((char*)SM + r * 128 + (((2 * mt + (quad >> 1)) ^ (r & 7)) << 4)
                          + (quad & 1) * 8) = pk;
            }
        }

        asm volatile("s_waitcnt vmcnt(0)" ::: "memory");   // V[kt] + K[kt+1] landed
        __builtin_amdgcn_s_barrier();

        if (kt + 2 < 16) {
            const unsigned short* ks = Ksrc + (size_t)(kt + 2) * 64 * 2048;
            GLL(ks, 8192 + cur * 4096);
            GLL(ks + (size_t)32 * 2048, 8192 + cur * 4096 + 2048);
        }

        // ---- O^T += V^T P^T ; l += ones^T P^T (row-sum via MFMA) ----
        bf16x8 pf[2][2];
#pragma unroll
        for (int nt2 = 0; nt2 < 2; nt2++)
#pragma unroll
            for (int kc = 0; kc < 2; kc++)
                pf[nt2][kc] = ldsfrag(SM, 0, wrow + nt2 * 16 + l15, kc * 4 + quad);
#pragma unroll
        for (int nt2 = 0; nt2 < 2; nt2++) {
            l_acc[nt2] = __builtin_amdgcn_mfma_f32_16x16x32_bf16(onesv, pf[nt2][0], l_acc[nt2], 0, 0, 0);
            l_acc[nt2] = __builtin_amdgcn_mfma_f32_16x16x32_bf16(onesv, pf[nt2][1], l_acc[nt2], 0, 0, 0);
        }
#pragma unroll
        for (int dt = 0; dt < 4; dt++) {
            bf16x8 vf0 = ldsfrag(SM, 16384, dt * 16 + l15, quad);
            bf16x8 vf1 = ldsfrag(SM, 16384, dt * 16 + l15, 4 + quad);
#pragma unroll
            for (int nt2 = 0; nt2 < 2; nt2++) {
                O[nt2][dt] = __builtin_amdgcn_mfma_f32_16x16x32_bf16(vf0, pf[nt2][0], O[nt2][dt], 0, 0, 0);
                O[nt2][dt] = __builtin_amdgcn_mfma_f32_16x16x32_bf16(vf1, pf[nt2][1], O[nt2][dt], 0, 0, 0);
            }
        }

        __builtin_amdgcn_s_barrier();
    }

    // ---- O^T -> LDS (bf16); coalesced residual add ----
    {
        float inv0 = 1.f / l_acc[0][0], inv1 = 1.f / l_acc[1][0];
#pragma unroll
        for (int nt2 = 0; nt2 < 2; nt2++) {
            float inv = (nt2 == 0) ? inv0 : inv1;
            const int r = wrow + nt2 * 16 + l15;
#pragma unroll
            for (int dt = 0; dt < 4; dt++) {
                uint2 pk;
                pk.x = cvt_pk_bf16u(O[nt2][dt][0] * inv, O[nt2][dt][1] * inv);
                pk.y = cvt_pk_bf16u(O[nt2][dt][2] * inv, O[nt2][dt][3] * inv);
                *(uint2*)((char*)SM + 16384 + r * 128 + (((2 * dt + (quad >> 1)) ^ (r & 7)) << 4)
                          + (quad & 1) * 8) = pk;
            }
        }
    }
    __syncthreads();
    {
        int r0 = t >> 2;
        int qc = t & 3;
#pragma unroll
        for (int half = 0; half < 2; half++) {
            int r = r0 + half * 64;
            size_t off = ((size_t)(b * 1024 + qt * 128 + r)) * 1024 + h * 64 + qc * 16;
            const float* xrp = xres + off;
            float* xwp = xout + off;
#pragma unroll
            for (int jj = 0; jj < 2; jj++) {
                uint4 u = *(const uint4*)((const char*)SM + 16384 + r * 128
                                          + (((qc * 2 + jj) ^ (r & 7)) << 4));
                f32x4 xv0 = *(const f32x4*)(xrp + jj * 8);
                f32x4 xv1 = *(const f32x4*)(xrp + jj * 8 + 4);
                xv0[0] += b2f((unsigned short)(u.x & 0xffff));
                xv0[1] += b2f((unsigned short)(u.x >> 16));
                xv0[2] += b2f((unsigned short)(u.y & 0xffff));
                xv0[3] += b2f((unsigned short)(u.y >> 16));
                xv1[0] += b2f((unsigned short)(u.z & 0xffff));
                xv1[1] += b2f((unsigned short)(u.z >> 16));
                xv1[2] += b2f((unsigned short)(u.w & 0xffff));
                xv1[3] += b2f((unsigned short)(u.w >> 16));
                *(f32x4*)(xwp + jj * 8)     = xv0;
                *(f32x4*)(xwp + jj * 8 + 4) = xv1;
            }
        }
    }
}

// ---------------- launch ----------------
extern "C" void kernel_launch(void* const* d_in, const int* in_sizes, int n_in,
                              void* d_out, int out_size, void* d_ws, size_t ws_size,
                              hipStream_t stream)
{
    (void)in_sizes; (void)n_in; (void)out_size; (void)ws_size;
    const float* x_in  = (const float*)d_in[0];
    const float* Wq    = (const float*)d_in[1];
    const float* bq    = (const float*)d_in[2];
    const float* Wk    = (const float*)d_in[3];
    const float* bk    = (const float*)d_in[4];
    const float* Wv    = (const float*)d_in[5];
    const float* bv    = (const float*)d_in[6];
    const float* W1    = (const float*)d_in[7];
    const float* b1    = (const float*)d_in[8];
    const float* W2    = (const float*)d_in[9];
    const float* b2    = (const float*)d_in[10];
    const float* gamma = (const float*)d_in[11];
    const float* beta  = (const float*)d_in[12];

    char* base = (char*)d_ws;
    float*          xf   = (float*)(base);                                // 32 MB
    unsigned short* xn   = (unsigned short*)(base + 33554432);            // 16 MB
    unsigned short* qkb  = (unsigned short*)(base + 50331648);            // 32 MB fused QK [8192][2048]
    unsigned short* vtb  = (unsigned short*)(base + 50331648 + 33554432); // 16 MB V^T [1024][8192]
    unsigned short* h1   = (unsigned short*)(base + 50331648);            // 64 MB (aliases qk/vt)
    char* wbase = base + 50331648 + 67108864;
    unsigned short* WqkT = (unsigned short*)(wbase);                      // 4 MB fused [2048][1024]
    unsigned short* WvT  = (unsigned short*)(wbase + 4194304);
    unsigned short* W1T  = (unsigned short*)(wbase + 6291456);
    unsigned short* W2T  = (unsigned short*)(wbase + 14680064);
    float*          bqk  = (float*)(wbase + 23068672);                    // 8 KB

    transpose3_f32_to_bf16<<<dim3(32, 32, 3), 256, 0, stream>>>(Wq, Wk, Wv, WqkT, WvT);
    transpose_f32_to_bf16<<<dim3(128, 32), 256, 0, stream>>>(W1, W1T, 1024, 4096);
    transpose_f32_to_bf16<<<dim3(32, 128), 256, 0, stream>>>(W2, W2T, 4096, 1024);
    concat_bias<<<8, 256, 0, stream>>>(bq, bk, bqk);

    for (int layer = 0; layer < 6; ++layer) {
        const float* xcur = (layer == 0) ? x_in : xf;   // residual stream source
        layernorm_k<<<4096, 256, 0, stream>>>(xcur, gamma, beta, xn);
        // fused QK: M=8192 N=2048, BN=256: 256 blocks, 128KB LDS
        gemm256<5, 3, 256><<<256, 512, 131072, stream>>>(xn, WqkT, bqk, nullptr, qkb, 8192, 2048, 1024);
        // V^T: M=1024 N=8192, SMALLM decode: 4m x 64n(BN=128) = 256 blocks, 96KB LDS
        gemm256<3, 0, 128, 1><<<256, 512, 98304, stream>>>(WvT, xn, bv, nullptr, vtb, 1024, 8192, 1024);
        // attn: residual read from xcur, write to xf
        attn_k<<<1024, 256, 0, stream>>>(qkb, vtb, xcur, xf);
        layernorm_k<<<4096, 256, 0, stream>>>(xf, gamma, beta, xn);
        // MLP up: M=8192 N=4096, 512 blocks, 128KB LDS
        gemm256<1, 4, 256><<<512, 512, 131072, stream>>>(xn, W1T, b1, nullptr, h1, 8192, 4096, 1024);
        // MLP down: M=8192 N=1024 K=4096, BN=128: 256 blocks, 96KB LDS
        float* mout = (layer == 5) ? (float*)d_out : xf;
        gemm256<2, 3, 128><<<256, 512, 98304, stream>>>(h1, W2T, b2, xf, mout, 8192, 1024, 4096);
    }
}

// Round 15
// 1824.684 us; speedup vs baseline: 1.0104x; 1.0104x over previous
//
#include <hip/hip_runtime.h>
#include <cstdint>
#include <cmath>

typedef short bf16x8 __attribute__((ext_vector_type(8)));
typedef float f32x4 __attribute__((ext_vector_type(4)));

#define AS_GLOBAL(p) (const __attribute__((address_space(1))) void*)(p)
#define AS_LDS(p)    (__attribute__((address_space(3))) void*)(p)

// SCALE * log2(e) folded into Q epilogue: 2^-5 * 1.44269504
#define QSCALE 0.04508422002778f

__device__ inline float b2f(unsigned short u) {
    union { unsigned int i; float f; } c; c.i = ((unsigned int)u) << 16; return c.f;
}
__device__ inline unsigned short f2b(float f) {
    return (unsigned short)((__float_as_uint(f) + 0x8000u) >> 16);
}
// HW packed f32->bf16 (RTNE), 1 inst per 2 floats (T12 recipe; no builtin on gfx950)
__device__ inline unsigned cvt_pk_bf16u(float lo, float hi) {
    unsigned r;
    asm("v_cvt_pk_bf16_f32 %0, %1, %2" : "=v"(r) : "v"(lo), "v"(hi));
    return r;
}
// fast GELU: x * sigmoid(1.5957691x + 0.071354816x^3), evaluated in exp2 domain.
__device__ inline float fast_gelu(float x) {
    float arg = -x * (2.30223674f + 0.10294946f * x * x);
    float t = exp2f(arg);
    return x * __builtin_amdgcn_rcpf(1.f + t);
}

// swizzled LDS fragment read: row r (pitch 128 B), logical 16B-chunk lc, chunk ^= r&7
__device__ inline bf16x8 ldsfrag(const unsigned short* SM, int base_sh, int r, int lc) {
    return *(const bf16x8*)((const char*)SM + base_sh * 2 + r * 128 + ((lc ^ (r & 7)) << 4));
}

// ---------------- weight transpose+cast: W[K][N] (f32) -> Wt[N][K] (bf16) ----------------
__global__ __launch_bounds__(256) void transpose_f32_to_bf16(
    const float* __restrict__ W, unsigned short* __restrict__ Wt, int K, int N)
{
    __shared__ unsigned short sh[32][33];
    int n0 = blockIdx.x * 32;
    int k0 = blockIdx.y * 32;
    int tr = threadIdx.x >> 5;
    int tc = threadIdx.x & 31;
#pragma unroll
    for (int i = 0; i < 4; i++)
        sh[tr + i * 8][tc] = f2b(W[(size_t)(k0 + tr + i * 8) * N + n0 + tc]);
    __syncthreads();
#pragma unroll
    for (int i = 0; i < 4; i++)
        Wt[(size_t)(n0 + tr + i * 8) * K + k0 + tc] = sh[tc][tr + i * 8];
}

// fused 3x 1024x1024 transpose (z selects Wq->WqkT, Wk->WqkT+1M, Wv->WvT)
__global__ __launch_bounds__(256) void transpose3_f32_to_bf16(
    const float* __restrict__ Wq, const float* __restrict__ Wk,
    const float* __restrict__ Wv, unsigned short* __restrict__ WqkT,
    unsigned short* __restrict__ WvT)
{
    __shared__ unsigned short sh[32][33];
    const float* W = (blockIdx.z == 0) ? Wq : (blockIdx.z == 1) ? Wk : Wv;
    unsigned short* Wt = (blockIdx.z == 0) ? WqkT
                        : (blockIdx.z == 1) ? (WqkT + 1048576) : WvT;
    int n0 = blockIdx.x * 32;
    int k0 = blockIdx.y * 32;
    int tr = threadIdx.x >> 5;
    int tc = threadIdx.x & 31;
#pragma unroll
    for (int i = 0; i < 4; i++)
        sh[tr + i * 8][tc] = f2b(W[(size_t)(k0 + tr + i * 8) * 1024 + n0 + tc]);
    __syncthreads();
#pragma unroll
    for (int i = 0; i < 4; i++)
        Wt[(size_t)(n0 + tr + i * 8) * 1024 + k0 + tc] = sh[tc][tr + i * 8];
}

// ---------------- bias concat: bqk = [bq | bk] ----------------
__global__ __launch_bounds__(256) void concat_bias(const float* __restrict__ bq,
                                                   const float* __restrict__ bk,
                                                   float* __restrict__ bqk)
{
    int i = blockIdx.x * 256 + threadIdx.x;
    bqk[i] = (i < 1024) ? bq[i] : bk[i - 1024];
}

// ---------------- layernorm: fp32 in -> bf16 out; 2 rows/block, 8 elems/thread ----------------
__global__ __launch_bounds__(256) void layernorm_k(
    const float* __restrict__ x, const float* __restrict__ gamma,
    const float* __restrict__ beta, unsigned short* __restrict__ out)
{
    const int t   = threadIdx.x;
    const int row = blockIdx.x * 2 + (t >> 7);
    const int c   = (t & 127) * 8;
    const float* xp = x + (size_t)row * 1024 + c;
    f32x4 v0 = *(const f32x4*)(xp);
    f32x4 v1 = *(const f32x4*)(xp + 4);
    float s  = v0[0] + v0[1] + v0[2] + v0[3] + v1[0] + v1[1] + v1[2] + v1[3];
    float s2 = v0[0]*v0[0] + v0[1]*v0[1] + v0[2]*v0[2] + v0[3]*v0[3]
             + v1[0]*v1[0] + v1[1]*v1[1] + v1[2]*v1[2] + v1[3]*v1[3];
#pragma unroll
    for (int off = 32; off >= 1; off >>= 1) {
        s  += __shfl_xor(s,  off);
        s2 += __shfl_xor(s2, off);
    }
    __shared__ float red[8];
    const int w = t >> 6;                 // wave 0..3; waves {0,1}=row0, {2,3}=row1
    if ((t & 63) == 0) { red[w] = s; red[4 + w] = s2; }
    __syncthreads();
    const int base = w & 2;
    s  = red[base] + red[base + 1];
    s2 = red[4 + base] + red[5 + base];
    float mu  = s * (1.f / 1024.f);
    float var = s2 * (1.f / 1024.f) - mu * mu;
    float rs  = rsqrtf(var + 1e-5f);
    f32x4 g0 = *(const f32x4*)(gamma + c);
    f32x4 g1 = *(const f32x4*)(gamma + c + 4);
    f32x4 b0 = *(const f32x4*)(beta + c);
    f32x4 b1 = *(const f32x4*)(beta + c + 4);
    uint4 pk;
    {
        float o0 = (v0[0] - mu) * rs * g0[0] + b0[0];
        float o1 = (v0[1] - mu) * rs * g0[1] + b0[1];
        float o2 = (v0[2] - mu) * rs * g0[2] + b0[2];
        float o3 = (v0[3] - mu) * rs * g0[3] + b0[3];
        float o4 = (v1[0] - mu) * rs * g1[0] + b1[0];
        float o5 = (v1[1] - mu) * rs * g1[1] + b1[1];
        float o6 = (v1[2] - mu) * rs * g1[2] + b1[2];
        float o7 = (v1[3] - mu) * rs * g1[3] + b1[3];
        pk.x = (unsigned)f2b(o0) | ((unsigned)f2b(o1) << 16);
        pk.y = (unsigned)f2b(o2) | ((unsigned)f2b(o3) << 16);
        pk.z = (unsigned)f2b(o4) | ((unsigned)f2b(o5) << 16);
        pk.w = (unsigned)f2b(o6) | ((unsigned)f2b(o7) << 16);
    }
    *(uint4*)(out + (size_t)row * 1024 + c) = pk;
}

// ---------------- 256-wide 8-phase MFMA GEMM body (round-11 schedule) ----------------
// BM=256, BK=64, 512 threads = 8 waves. Wave grid: WGN = BN/64 waves along N,
// 8/WGN along M -> per-wave sub-tile (32*WGN rows) x 64 cols.
// Phase pipeline: phase p issues phase p+1's ds_reads BEFORE the phase barrier,
// waits counted lgkmcnt + sched_barrier, then runs the MFMA cluster.
// STAGE split 2 gload_lds per phase; tile-end vmcnt(0)+barrier.
// Decode: SMALLM=0: m-fastest within XCD; SMALLM=1 (M=1024): m=j>>3, n=xcd*8+(j&7).
// MODE 1: bf16 out = fast_gelu(v + bias[col])
// MODE 2: f32 out = resid[idx] + v + bias[col]   (resid may alias out)
// MODE 3: bf16 out = v + bias[row]               (V^T GEMM)
// MODE 5: bf16 out = (v + bias[col]) * (col<1024 ? QSCALE : 1)
template<int MODE, int NBNL, int BN, int SMALLM>
__device__ __forceinline__ void gemm256_body(
    const unsigned short* __restrict__ A,
    const unsigned short* __restrict__ Bt,
    const float* __restrict__ bias,
    const float* __restrict__ resid,
    void* __restrict__ outp,
    int M, int N, int K, int bi, unsigned short* LDS)
{
    constexpr int NFR = BN / 64;          // B row-groups to stage per thread
    constexpr int WGN = BN / 64;          // waves along N (4 or 2)
    constexpr int WM  = 2 * WGN;          // m-frags per wave (8 or 4)
    constexpr int HM  = WM / 2;           // m-frags per phase (4 or 2)

    const int t   = threadIdx.x;
    const int xcd = bi & 7;
    const int j   = bi >> 3;
    int m_idx, n_idx;
    if (SMALLM) {                         // M = 1024: 4 m-tiles x (8*8) n-tiles
        m_idx = j >> 3;
        n_idx = xcd * 8 + (j & 7);
    } else {                              // m-fastest within XCD (less L2 thrash)
        const int mper = M >> 11;         // m-tiles per XCD (power of 2)
        m_idx = xcd * mper + (j & (mper - 1));
        n_idx = j >> __builtin_ctz(mper);
    }
    const int m0 = m_idx * 256;
    const int n0 = n_idx * BN;

    const int w    = t >> 6;
    const int lane = t & 63;
    const int l15  = lane & 15;
    const int q    = lane >> 4;
    const int wmb  = (w / WGN) * (WM * 16);   // row base of wave's sub-tile
    const int wnb  = (w % WGN) * 64;          // col base of wave's sub-tile
    const int xsw  = (l15 & 7) << 4;          // read-side swizzle (byte)

    const int trow = t >> 3;
    const int csrc = ((t & 7) ^ (trow & 7)) << 3;     // element offset in row
    const unsigned short* As0 = A  + (size_t)(m0 + trow) * K + csrc;
    const unsigned short* Bs0 = Bt + (size_t)(n0 + trow) * K + csrc;

    f32x4 acc[WM][4];
#pragma unroll
    for (int i = 0; i < WM; i++)
#pragma unroll
        for (int n = 0; n < 4; n++) acc[i][n] = (f32x4)0.f;

    // staging split into 4 parts, 2 gload_lds each (BN=128: part 3 empty)
    auto STAGEP = [&](int Tn, int part) {
        const int bsel = Tn & 1;
        const size_t kk = (size_t)Tn << 6;
        if (part < 2) {
#pragma unroll
            for (int la = part * 2; la < part * 2 + 2; la++)
                __builtin_amdgcn_global_load_lds(
                    AS_GLOBAL(As0 + (size_t)la * 64 * K + kk),
                    AS_LDS(LDS + bsel * 16384 + la * 4096 + w * 512), 16, 0, 0);
        } else {
#pragma unroll
            for (int lb = (part - 2) * 2; lb < (part - 2) * 2 + 2; lb++)
                if (lb < NFR)
                    __builtin_amdgcn_global_load_lds(
                        AS_GLOBAL(Bs0 + (size_t)lb * 64 * K + kk),
                        AS_LDS(LDS + 32768 + bsel * (BN * 64) + lb * 4096 + w * 512), 16, 0, 0);
        }
    };
    auto RDAF = [&](const char* Ab, int ks, int mh, bf16x8* dst) {
        const int colx = ((ks * 64 + q * 16) ^ xsw);
#pragma unroll
        for (int m4 = 0; m4 < HM; m4++)
            dst[m4] = *(const bf16x8*)(Ab + (wmb + (mh * HM + m4) * 16 + l15) * 128 + colx);
    };
    auto RDBV = [&](const char* Bb, int ks, bf16x8* dst) {
        const int colx = ((ks * 64 + q * 16) ^ xsw);
#pragma unroll
        for (int ni = 0; ni < 4; ni++)
            dst[ni] = *(const bf16x8*)(Bb + (wnb + ni * 16 + l15) * 128 + colx);
    };
    auto MM = [&](int mh, bf16x8* afs, bf16x8* bvs) {
        __builtin_amdgcn_s_setprio(1);
#pragma unroll
        for (int m4 = 0; m4 < HM; m4++)
#pragma unroll
            for (int ni = 0; ni < 4; ni++)
                acc[mh * HM + m4][ni] = __builtin_amdgcn_mfma_f32_16x16x32_bf16(
                    afs[m4], bvs[ni], acc[mh * HM + m4][ni], 0, 0, 0);
        __builtin_amdgcn_s_setprio(0);
        __builtin_amdgcn_sched_barrier(0);
    };

    bf16x8 afA[HM], afB[HM], bvA[4], bvB[4];

    // prologue: stage tile 0 fully, drain, read phase-0 fragments
    STAGEP(0, 0); STAGEP(0, 1); STAGEP(0, 2); STAGEP(0, 3);
    asm volatile("s_waitcnt vmcnt(0)" ::: "memory");
    __builtin_amdgcn_s_barrier();
    RDBV((const char*)LDS + 65536, 0, bvA);
    RDAF((const char*)LDS, 0, 0, afA);

    const int NT = K >> 6;
    for (int T = 0; T < NT; T++) {
        const char* Ab = (const char*)LDS + (T & 1) * 32768;
        const char* Bb = (const char*)LDS + 65536 + (T & 1) * (BN * 128);
        const bool pf = (T + 1 < NT);

        // phase 0: consume (ks0,mh0)=afA,bvA ; prefetch afB=(ks0,mh1)
        RDAF(Ab, 0, 1, afB);
        if (pf) STAGEP(T + 1, 0);
        __builtin_amdgcn_s_barrier();
        if (BN == 256) asm volatile("s_waitcnt lgkmcnt(4)" ::: "memory");
        else           asm volatile("s_waitcnt lgkmcnt(2)" ::: "memory");
        __builtin_amdgcn_sched_barrier(0);
        MM(0, afA, bvA);

        // phase 1: consume (ks0,mh1)=afB,bvA ; prefetch bvB(ks1), afA=(ks1,mh0)
        RDBV(Bb, 1, bvB);
        RDAF(Ab, 1, 0, afA);
        if (pf) STAGEP(T + 1, 1);
        __builtin_amdgcn_s_barrier();
        if (BN == 256) asm volatile("s_waitcnt lgkmcnt(8)" ::: "memory");
        else           asm volatile("s_waitcnt lgkmcnt(6)" ::: "memory");
        __builtin_amdgcn_sched_barrier(0);
        MM(1, afB, bvA);

        // phase 2: consume (ks1,mh0)=afA,bvB ; prefetch afB=(ks1,mh1)
        RDAF(Ab, 1, 1, afB);
        if (pf) STAGEP(T + 1, 2);
        __builtin_amdgcn_s_barrier();
        if (BN == 256) asm volatile("s_waitcnt lgkmcnt(4)" ::: "memory");
        else           asm volatile("s_waitcnt lgkmcnt(2)" ::: "memory");
        __builtin_amdgcn_sched_barrier(0);
        MM(0, afA, bvB);

        // phase 3: consume (ks1,mh1)=afB,bvB ; lgkmcnt(0) -> WAR-safe for T+1 staging
        if (pf) STAGEP(T + 1, 3);
        __builtin_amdgcn_s_barrier();
        asm volatile("s_waitcnt lgkmcnt(0)" ::: "memory");
        __builtin_amdgcn_sched_barrier(0);
        MM(1, afB, bvB);

        // tile boundary: drain staged loads, then prefetch next tile's phase-0 frags
        asm volatile("s_waitcnt vmcnt(0)" ::: "memory");
        __builtin_amdgcn_s_barrier();
        if (pf) {
            const char* AbN = (const char*)LDS + ((T + 1) & 1) * 32768;
            const char* BbN = (const char*)LDS + 65536 + ((T + 1) & 1) * (BN * 128);
            RDBV(BbN, 0, bvA);
            RDAF(AbN, 0, 0, afA);
        }
    }

    const float qsc = (MODE == 5 && n0 < 1024) ? QSCALE : 1.f;
#pragma unroll
    for (int mi = 0; mi < WM; mi++) {
        const int gr0 = m0 + wmb + mi * 16 + q * 4;
#pragma unroll
        for (int ni = 0; ni < 4; ni++) {
            const int gc = n0 + wnb + ni * 16 + l15;
            const float bv = (MODE == 3) ? 0.f : bias[gc];
#pragma unroll
            for (int r = 0; r < 4; r++) {
                const int gr = gr0 + r;
                float v = acc[mi][ni][r] + ((MODE == 3) ? bias[gr] : bv);
                if (MODE == 1) {
                    ((unsigned short*)outp)[(size_t)gr * N + gc] = f2b(fast_gelu(v));
                } else if (MODE == 2) {
                    ((float*)outp)[(size_t)gr * N + gc] = resid[(size_t)gr * N + gc] + v;
                } else if (MODE == 3) {
                    ((unsigned short*)outp)[(size_t)gr * N + gc] = f2b(v);
                } else { // MODE 5
                    ((unsigned short*)outp)[(size_t)gr * N + gc] = f2b(v * qsc);
                }
            }
        }
    }
}

template<int MODE, int NBNL, int BN, int SMALLM = 0>
__global__ __launch_bounds__(512, 2) void gemm256(
    const unsigned short* __restrict__ A,
    const unsigned short* __restrict__ Bt,
    const float* __restrict__ bias,
    const float* __restrict__ resid,
    void* __restrict__ outp,
    int M, int N, int K)
{
    extern __shared__ unsigned short LDS[];
    gemm256_body<MODE, NBNL, BN, SMALLM>(A, Bt, bias, resid, outp, M, N, K,
                                         blockIdx.x, LDS);
}

// fused QK + V^T dispatch: blocks 0-255 = QK (MODE 5, BN=256), 256-511 = V^T
// (MODE 3, SMALLM, BN=128). Both read only xn; merging lets V^T blocks backfill
// CUs as QK blocks retire (QK is 1 block/CU -> exposed tail otherwise).
__global__ __launch_bounds__(512, 2) void qkv_fused(
    const unsigned short* __restrict__ xn,
    const unsigned short* __restrict__ WqkT,
    const float* __restrict__ bqk,
    unsigned short* __restrict__ qkb,
    const unsigned short* __restrict__ WvT,
    const float* __restrict__ bv,
    unsigned short* __restrict__ vtb)
{
    extern __shared__ unsigned short LDS[];
    if (blockIdx.x < 256) {
        gemm256_body<5, 3, 256, 0>(xn, WqkT, bqk, nullptr, qkb,
                                   8192, 2048, 1024, blockIdx.x, LDS);
    } else {
        gemm256_body<3, 0, 128, 1>(WvT, xn, bv, nullptr, vtb,
                                   1024, 8192, 1024, blockIdx.x - 256, LDS);
    }
}

// ---------------- MFMA flash attention v6 ----------------
// grid = 1024. XCD-locality decode: qt = blk>>7, bh = blk&127.
// 4 waves x 32 q-rows; 16 K-tiles of 64. l row-sum via MFMA ones-trick,
// P/O bf16 packing via v_cvt_pk_bf16_f32. Residual read xres, output xout.
__global__ __launch_bounds__(256, 4) void attn_k(
    const unsigned short* __restrict__ qkb,
    const unsigned short* __restrict__ vtb,
    const float* __restrict__ xres,
    float* __restrict__ xout)
{
    __shared__ unsigned short SM[20480];

    const int t    = threadIdx.x;
    const int blk  = blockIdx.x;
    const int qt   = blk >> 7;
    const int bh   = blk & 127;
    const int h    = bh & 15;
    const int b    = bh >> 4;
    const int w    = t >> 6;
    const int lane = t & 63;
    const int l15  = lane & 15;
    const int quad = lane >> 4;
    const int wrow = w * 32;

    const int sr  = t >> 3;                       // 0..31
    const int slc = (t & 7) ^ (sr & 7);
    const unsigned short* Qsrc = qkb + ((size_t)(b * 1024 + qt * 128 + sr)) * 2048 + h * 64 + slc * 8;
    const unsigned short* Ksrc = qkb + ((size_t)(b * 1024 + sr)) * 2048 + 1024 + h * 64 + slc * 8;
    const unsigned short* Vsrc = vtb + ((size_t)(h * 64 + sr)) * 8192 + (size_t)b * 1024 + slc * 8;

    auto GLL = [&](const unsigned short* g, int sh) {
        __builtin_amdgcn_global_load_lds(AS_GLOBAL(g), AS_LDS(SM + sh + w * 512), 16, 0, 0);
    };

    // ---- prologue: stage Q (128 rows), K[0], K[1], V[0] ----
#pragma unroll
    for (int c = 0; c < 4; c++) GLL(Qsrc + (size_t)c * 32 * 2048, c * 2048);
#pragma unroll
    for (int c = 0; c < 2; c++) GLL(Ksrc + (size_t)c * 32 * 2048, 8192 + c * 2048);
#pragma unroll
    for (int c = 0; c < 2; c++) GLL(Ksrc + (size_t)(64 + c * 32) * 2048, 12288 + c * 2048);
#pragma unroll
    for (int c = 0; c < 2; c++) GLL(Vsrc + (size_t)c * 32 * 8192, 16384 + c * 2048);
    asm volatile("s_waitcnt vmcnt(0)" ::: "memory");
    __builtin_amdgcn_s_barrier();

    bf16x8 qf[2][2];
#pragma unroll
    for (int nt2 = 0; nt2 < 2; nt2++)
#pragma unroll
        for (int kd = 0; kd < 2; kd++)
            qf[nt2][kd] = ldsfrag(SM, 0, wrow + nt2 * 16 + l15, kd * 4 + quad);

    const bf16x8 onesv = (bf16x8)(short)0x3F80;   // bf16 1.0 x8
    float m_s[2] = { -1e30f, -1e30f };
    f32x4 l_acc[2] = { (f32x4)0.f, (f32x4)0.f };
    f32x4 O[2][4];
#pragma unroll
    for (int nt2 = 0; nt2 < 2; nt2++)
#pragma unroll
        for (int dt = 0; dt < 4; dt++) O[nt2][dt] = (f32x4)0.f;

    for (int kt = 0; kt < 16; ++kt) {
        const int cur = kt & 1;
        if (kt > 0) {
            const unsigned short* vs = Vsrc + kt * 64;
            GLL(vs, 16384);
            GLL(vs + (size_t)32 * 8192, 16384 + 2048);
        }

        // ---- S^T = K Q^T ----
        f32x4 s[4][2];
#pragma unroll
        for (int mt = 0; mt < 4; mt++) {
            bf16x8 kf0 = ldsfrag(SM, 8192 + cur * 4096, mt * 16 + l15, quad);
            bf16x8 kf1 = ldsfrag(SM, 8192 + cur * 4096, mt * 16 + l15, 4 + quad);
#pragma unroll
            for (int nt2 = 0; nt2 < 2; nt2++) {
                f32x4 a = (f32x4)0.f;
                a = __builtin_amdgcn_mfma_f32_16x16x32_bf16(kf0, qf[nt2][0], a, 0, 0, 0);
                a = __builtin_amdgcn_mfma_f32_16x16x32_bf16(kf1, qf[nt2][1], a, 0, 0, 0);
                s[mt][nt2] = a;
            }
        }

        // ---- online softmax (exp2 domain), defer-max THR=0 (exact);
        //      exp -> cvt_pk -> P^T LDS store fused; l via MFMA below ----
#pragma unroll
        for (int nt2 = 0; nt2 < 2; nt2++) {
            float tm = -1e30f;
#pragma unroll
            for (int mt = 0; mt < 4; mt++) {
                f32x4 sv = s[mt][nt2];
                tm = fmaxf(tm, fmaxf(fmaxf(sv[0], sv[1]), fmaxf(sv[2], sv[3])));
            }
            tm = fmaxf(tm, __shfl_xor(tm, 16));
            tm = fmaxf(tm, __shfl_xor(tm, 32));
            if (!__all(tm <= m_s[nt2])) {
                float nm    = fmaxf(m_s[nt2], tm);
                float alpha = exp2f(m_s[nt2] - nm);
                m_s[nt2] = nm;
                l_acc[nt2] *= alpha;
#pragma unroll
                for (int dt = 0; dt < 4; dt++) O[nt2][dt] *= alpha;
            }
            const float nm = m_s[nt2];
            const int r = wrow + nt2 * 16 + l15;
#pragma unroll
            for (int mt = 0; mt < 4; mt++) {
                float p0 = exp2f(s[mt][nt2][0] - nm);
                float p1 = exp2f(s[mt][nt2][1] - nm);
                float p2 = exp2f(s[mt][nt2][2] - nm);
                float p3 = exp2f(s[mt][nt2][3] - nm);
                uint2 pk;
                pk.x = cvt_pk_bf16u(p0, p1);
                pk.y = cvt_pk_bf16u(p2, p3);
                *(uint2*)((char*)SM + r * 128 + (((2 * mt + (quad >> 1)) ^ (r & 7)) << 4)
                          + (quad & 1) * 8) = pk;
            }
        }

        asm volatile("s_waitcnt vmcnt(0)" ::: "memory");   // V[kt] + K[kt+1] landed
        __builtin_amdgcn_s_barrier();

        if (kt + 2 < 16) {
            const unsigned short* ks = Ksrc + (size_t)(kt + 2) * 64 * 2048;
            GLL(ks, 8192 + cur * 4096);
            GLL(ks + (size_t)32 * 2048, 8192 + cur * 4096 + 2048);
        }

        // ---- O^T += V^T P^T ; l += ones^T P^T (row-sum via MFMA) ----
        bf16x8 pf[2][2];
#pragma unroll
        for (int nt2 = 0; nt2 < 2; nt2++)
#pragma unroll
            for (int kc = 0; kc < 2; kc++)
                pf[nt2][kc] = ldsfrag(SM, 0, wrow + nt2 * 16 + l15, kc * 4 + quad);
#pragma unroll
        for (int nt2 = 0; nt2 < 2; nt2++) {
            l_acc[nt2] = __builtin_amdgcn_mfma_f32_16x16x32_bf16(onesv, pf[nt2][0], l_acc[nt2], 0, 0, 0);
            l_acc[nt2] = __builtin_amdgcn_mfma_f32_16x16x32_bf16(onesv, pf[nt2][1], l_acc[nt2], 0, 0, 0);
        }
#pragma unroll
        for (int dt = 0; dt < 4; dt++) {
            bf16x8 vf0 = ldsfrag(SM, 16384, dt * 16 + l15, quad);
            bf16x8 vf1 = ldsfrag(SM, 16384, dt * 16 + l15, 4 + quad);
#pragma unroll
            for (int nt2 = 0; nt2 < 2; nt2++) {
                O[nt2][dt] = __builtin_amdgcn_mfma_f32_16x16x32_bf16(vf0, pf[nt2][0], O[nt2][dt], 0, 0, 0);
                O[nt2][dt] = __builtin_amdgcn_mfma_f32_16x16x32_bf16(vf1, pf[nt2][1], O[nt2][dt], 0, 0, 0);
            }
        }

        __builtin_amdgcn_s_barrier();
    }

    // ---- O^T -> LDS (bf16); coalesced residual add ----
    {
        float inv0 = 1.f / l_acc[0][0], inv1 = 1.f / l_acc[1][0];
#pragma unroll
        for (int nt2 = 0; nt2 < 2; nt2++) {
            float inv = (nt2 == 0) ? inv0 : inv1;
            const int r = wrow + nt2 * 16 + l15;
#pragma unroll
            for (int dt = 0; dt < 4; dt++) {
                uint2 pk;
                pk.x = cvt_pk_bf16u(O[nt2][dt][0] * inv, O[nt2][dt][1] * inv);
                pk.y = cvt_pk_bf16u(O[nt2][dt][2] * inv, O[nt2][dt][3] * inv);
                *(uint2*)((char*)SM + 16384 + r * 128 + (((2 * dt + (quad >> 1)) ^ (r & 7)) << 4)
                          + (quad & 1) * 8) = pk;
            }
        }
    }
    __syncthreads();
    {
        int r0 = t >> 2;
        int qc = t & 3;
#pragma unroll
        for (int half = 0; half < 2; half++) {
            int r = r0 + half * 64;
            size_t off = ((size_t)(b * 1024 + qt * 128 + r)) * 1024 + h * 64 + qc * 16;
            const float* xrp = xres + off;
            float* xwp = xout + off;
#pragma unroll
            for (int jj = 0; jj < 2; jj++) {
                uint4 u = *(const uint4*)((const char*)SM + 16384 + r * 128
                                          + (((qc * 2 + jj) ^ (r & 7)) << 4));
                f32x4 xv0 = *(const f32x4*)(xrp + jj * 8);
                f32x4 xv1 = *(const f32x4*)(xrp + jj * 8 + 4);
                xv0[0] += b2f((unsigned short)(u.x & 0xffff));
                xv0[1] += b2f((unsigned short)(u.x >> 16));
                xv0[2] += b2f((unsigned short)(u.y & 0xffff));
                xv0[3] += b2f((unsigned short)(u.y >> 16));
                xv1[0] += b2f((unsigned short)(u.z & 0xffff));
                xv1[1] += b2f((unsigned short)(u.z >> 16));
                xv1[2] += b2f((unsigned short)(u.w & 0xffff));
                xv1[3] += b2f((unsigned short)(u.w >> 16));
                *(f32x4*)(xwp + jj * 8)     = xv0;
                *(f32x4*)(xwp + jj * 8 + 4) = xv1;
            }
        }
    }
}

// ---------------- launch ----------------
extern "C" void kernel_launch(void* const* d_in, const int* in_sizes, int n_in,
                              void* d_out, int out_size, void* d_ws, size_t ws_size,
                              hipStream_t stream)
{
    (void)in_sizes; (void)n_in; (void)out_size; (void)ws_size;
    const float* x_in  = (const float*)d_in[0];
    const float* Wq    = (const float*)d_in[1];
    const float* bq    = (const float*)d_in[2];
    const float* Wk    = (const float*)d_in[3];
    const float* bk    = (const float*)d_in[4];
    const float* Wv    = (const float*)d_in[5];
    const float* bv    = (const float*)d_in[6];
    const float* W1    = (const float*)d_in[7];
    const float* b1    = (const float*)d_in[8];
    const float* W2    = (const float*)d_in[9];
    const float* b2    = (const float*)d_in[10];
    const float* gamma = (const float*)d_in[11];
    const float* beta  = (const float*)d_in[12];

    char* base = (char*)d_ws;
    float*          xf   = (float*)(base);                                // 32 MB
    unsigned short* xn   = (unsigned short*)(base + 33554432);            // 16 MB
    unsigned short* qkb  = (unsigned short*)(base + 50331648);            // 32 MB fused QK [8192][2048]
    unsigned short* vtb  = (unsigned short*)(base + 50331648 + 33554432); // 16 MB V^T [1024][8192]
    unsigned short* h1   = (unsigned short*)(base + 50331648);            // 64 MB (aliases qk/vt)
    char* wbase = base + 50331648 + 67108864;
    unsigned short* WqkT = (unsigned short*)(wbase);                      // 4 MB fused [2048][1024]
    unsigned short* WvT  = (unsigned short*)(wbase + 4194304);
    unsigned short* W1T  = (unsigned short*)(wbase + 6291456);
    unsigned short* W2T  = (unsigned short*)(wbase + 14680064);
    float*          bqk  = (float*)(wbase + 23068672);                    // 8 KB

    transpose3_f32_to_bf16<<<dim3(32, 32, 3), 256, 0, stream>>>(Wq, Wk, Wv, WqkT, WvT);
    transpose_f32_to_bf16<<<dim3(128, 32), 256, 0, stream>>>(W1, W1T, 1024, 4096);
    transpose_f32_to_bf16<<<dim3(32, 128), 256, 0, stream>>>(W2, W2T, 4096, 1024);
    concat_bias<<<8, 256, 0, stream>>>(bq, bk, bqk);

    for (int layer = 0; layer < 6; ++layer) {
        const float* xcur = (layer == 0) ? x_in : xf;   // residual stream source
        layernorm_k<<<4096, 256, 0, stream>>>(xcur, gamma, beta, xn);
        // fused QK (blocks 0-255) + V^T (blocks 256-511), 128KB LDS
        qkv_fused<<<512, 512, 131072, stream>>>(xn, WqkT, bqk, qkb, WvT, bv, vtb);
        // attn: residual read from xcur, write to xf
        attn_k<<<1024, 256, 0, stream>>>(qkb, vtb, xcur, xf);
        layernorm_k<<<4096, 256, 0, stream>>>(xf, gamma, beta, xn);
        // MLP up: M=8192 N=4096, 512 blocks, 128KB LDS
        gemm256<1, 4, 256><<<512, 512, 131072, stream>>>(xn, W1T, b1, nullptr, h1, 8192, 4096, 1024);
        // MLP down: M=8192 N=1024 K=4096, BN=128: 256 blocks, 96KB LDS
        float* mout = (layer == 5) ? (float*)d_out : xf;
        gemm256<2, 3, 128><<<256, 512, 98304, stream>>>(h1, W2T, b2, xf, mout, 8192, 1024, 4096);
    }
}